// Round 1
// baseline (75.401 us; speedup 1.0000x reference)
//
#include <hip/hip_runtime.h>

// Geometric product in Cl(3,2,1), DIM=64.
// out[n,k] = sum_a sign(a, a^k) * x[n,a] * y[n,a^k]
// Signs are compile-time: folded into FMA negate modifiers; zero terms elided.

__host__ __device__ constexpr int popc6(int v) {
  int c = 0;
  for (int i = 0; i < 6; ++i) c += (v >> i) & 1;
  return c;
}

// Faithful to the reference _cayley_tables(3,2,1):
//  - swap parity: for each bit set in a, count set bits of b below that bit
//  - neg dims: bits 3,4 (e3^2 = e4^2 = -1)
//  - null dim: bit 5 (e5^2 = 0)
__host__ __device__ constexpr int sign_ab(int a, int b) {
  int swap = 0;
  for (int bit = 0; bit < 6; ++bit)
    if ((a >> bit) & 1) swap += popc6(b & ((1 << bit) - 1));
  int s = (swap & 1) ? -1 : 1;
  if (popc6(a & b & 0x18) & 1) s = -s;  // negative dims: bits 3,4
  if (a & b & 0x20) s = 0;              // null dim: bit 5
  return s;
}

// Fully compile-time-unrolled term: k = Q + 4*KK  (wave q owns k === q mod 4,
// balanced: every wave gets 8 k's with bit5=0 and 8 with bit5=1 -> 768 FMA each)
template <int Q, int A, int KK>
__device__ __forceinline__ void do_terms(float xa, const float (&y)[64], float (&acc)[16]) {
  constexpr int k = Q + 4 * KK;
  constexpr int b = A ^ k;
  constexpr int sg = sign_ab(A, b);
  if constexpr (sg > 0)      acc[KK] = fmaf( xa, y[b], acc[KK]);
  else if constexpr (sg < 0) acc[KK] = fmaf(-xa, y[b], acc[KK]);
  if constexpr (KK + 1 < 16) do_terms<Q, A, KK + 1>(xa, y, acc);
}

template <int Q, int A>
__device__ __forceinline__ void do_a(const float* __restrict__ xrow, const float (&y)[64],
                                     float (&acc)[16]) {
  float xa = xrow[A];  // ds_read with compile-time immediate offset; stride-65 row -> 2-way bank (free)
  do_terms<Q, A, 0>(xa, y, acc);
  if constexpr (A + 1 < 64) do_a<Q, A + 1>(xrow, y, acc);
}

__global__ __launch_bounds__(256, 4) void clgp_kernel(const float* __restrict__ xg,
                                                      const float* __restrict__ yg,
                                                      float* __restrict__ og) {
  // LDS tiles padded to stride 65 floats (65 % 32 == 1 -> scalar row reads are
  // 2-way bank-aliased = free; stride 64 would be a 32-way conflict).
  __shared__ float xl[64 * 65];
  __shared__ float yl[64 * 65];

  const int t = threadIdx.x;
  const long tile = (long)blockIdx.x * 4096;  // 64 rows * 64 cols (floats)

  // ---- stage x,y: coalesced global float4 -> reg -> padded LDS ----
  const float4* x4 = (const float4*)(xg + tile);
  const float4* y4 = (const float4*)(yg + tile);
  float4 rx[4], ry[4];
#pragma unroll
  for (int p = 0; p < 4; ++p) {
    rx[p] = x4[t + p * 256];
    ry[p] = y4[t + p * 256];
  }
#pragma unroll
  for (int p = 0; p < 4; ++p) {
    const int v = t + p * 256;               // float4 index within tile
    const int w = (v >> 4) * 65 + (v & 15) * 4;
    xl[w + 0] = rx[p].x; xl[w + 1] = rx[p].y; xl[w + 2] = rx[p].z; xl[w + 3] = rx[p].w;
    yl[w + 0] = ry[p].x; yl[w + 1] = ry[p].y; yl[w + 2] = ry[p].z; yl[w + 3] = ry[p].w;
  }
  __syncthreads();

  const int lane = t & 63;  // batch row within tile
  const int q = t >> 6;     // wave id = k residue class mod 4 (wave-uniform)

  // y row -> 64 registers
  float yv[64];
  {
    const float* yrow = &yl[lane * 65];
#pragma unroll
    for (int j = 0; j < 64; ++j) yv[j] = yrow[j];
  }

  float acc[16];
#pragma unroll
  for (int i = 0; i < 16; ++i) acc[i] = 0.0f;

  const float* xrow = &xl[lane * 65];
  switch (q) {  // wave-uniform branch -> no divergence
    case 0: do_a<0, 0>(xrow, yv, acc); break;
    case 1: do_a<1, 0>(xrow, yv, acc); break;
    case 2: do_a<2, 0>(xrow, yv, acc); break;
    default: do_a<3, 0>(xrow, yv, acc); break;
  }

  __syncthreads();  // all waves done reading xl
  // transpose acc back through LDS (reuse xl) for coalesced stores
#pragma unroll
  for (int kk = 0; kk < 16; ++kk) xl[lane * 65 + q + 4 * kk] = acc[kk];
  __syncthreads();

  float4* o4 = (float4*)(og + tile);
#pragma unroll
  for (int p = 0; p < 4; ++p) {
    const int v = t + p * 256;
    const int w = (v >> 4) * 65 + (v & 15) * 4;
    float4 o;
    o.x = xl[w + 0]; o.y = xl[w + 1]; o.z = xl[w + 2]; o.w = xl[w + 3];
    o4[v] = o;
  }
}

extern "C" void kernel_launch(void* const* d_in, const int* in_sizes, int n_in,
                              void* d_out, int out_size, void* d_ws, size_t ws_size,
                              hipStream_t stream) {
  const float* x = (const float*)d_in[0];
  const float* y = (const float*)d_in[1];
  float* out = (float*)d_out;
  const int n_batch = in_sizes[0] / 64;
  const int grid = n_batch / 64;  // 65536/64 = 1024 blocks, 256 threads each
  clgp_kernel<<<grid, 256, 0, stream>>>(x, y, out);
}